// Round 9
// baseline (1179.481 us; speedup 1.0000x reference)
//
#include <hip/hip_runtime.h>
#include <hip/hip_bf16.h>

// Grouped GEMM (MoE): out[t,o] = sum_k x[t,k]*W[e,o,k] + bias[e,o]
// E=64, 4096 tok/expert, D_IN=D_OUT=512, f32 in/out. bf16 MFMA.
// R9 = R7 schedule (best measured: B via global_load_lds from pre-packed bf16 W,
// A reg-staged dist-2 into XOR-swizzled LDS, counted vmcnt, 1 barrier/step)
// + __launch_bounds__(256,3): 48KB LDS x 3 blocks/CU = 12 waves/CU so
// cross-block TLP absorbs the per-block barrier/LDS-burst critical path.

#define NEXPERT 64
#define DIN 512
#define DOUT 512
#define TPE 4096
#define BM 128
#define BN 256
#define BK 32
#define NKT 16

typedef __attribute__((ext_vector_type(8))) __bf16 bf16x8;
typedef __attribute__((ext_vector_type(4))) __bf16 bf16x4;
typedef __attribute__((ext_vector_type(4))) float f32x4;

// ---------------- W pack kernel: f32 W -> bf16 d_ws in gload_lds order ------
// Slot S = (((e*2+nt)*16 + kt)*16 + c)*64 + l  holds 8 bf16:
//   row o = nt*256 + c*16 + (l>>2),  k = kt*32 + kg(l)*8..,  kg(l)=(l&3)^((l>>3)&3)
// so a linear gload_lds fill of chunk c reproduces LDS layout
//   byte(row,kg) = row*64 + (kg ^ ((row>>1)&3))*16   (the proven XOR swizzle).
__global__ __launch_bounds__(256)
void pack_w_kernel(const float* __restrict__ w, __bf16* __restrict__ wp) {
  int S = blockIdx.x * 256 + threadIdx.x;          // 0 .. 2^21-1
  int l  = S & 63;
  int c  = (S >> 6) & 15;
  int kt = (S >> 10) & 15;
  int nt = (S >> 14) & 1;
  int e  = S >> 15;
  int o  = nt * 256 + c * 16 + (l >> 2);
  int kg = (l & 3) ^ ((l >> 3) & 3);
  const float* src = w + ((size_t)(e * DOUT + o)) * DIN + kt * BK + kg * 8;
  f32x4 lo = *(const f32x4*)(src);
  f32x4 hi = *(const f32x4*)(src + 4);
  bf16x8 r;
  r[0]=(__bf16)lo[0]; r[1]=(__bf16)lo[1]; r[2]=(__bf16)lo[2]; r[3]=(__bf16)lo[3];
  r[4]=(__bf16)hi[0]; r[5]=(__bf16)hi[1]; r[6]=(__bf16)hi[2]; r[7]=(__bf16)hi[3];
  *(bf16x8*)(wp + (size_t)S * 8) = r;
}

// ---------------- main kernel ----------------------------------------------
__global__ __launch_bounds__(256, 3)
void moe_gemm8(const float* __restrict__ x, const __bf16* __restrict__ wp,
               const float* __restrict__ bias, float* __restrict__ out) {
  __shared__ __align__(16) unsigned char sA[2][BM * BK * 2];  // 8KB each
  __shared__ __align__(16) unsigned char sB[2][BN * BK * 2];  // 16KB each

  // XCD swizzle: 4096 blocks = 8 XCDs x 512 contiguous.
  int bid = blockIdx.x;
  int swzb = (bid & 7) * 512 + (bid >> 3);
  int e  = swzb >> 6;
  int rr = swzb & 63;
  int mt = rr >> 1;      // A-panel shared by 2 consecutive blocks (nt inner)
  int nt = rr & 1;

  const int tid  = threadIdx.x;
  const int lane = tid & 63;
  const int wn   = tid >> 6;     // wave 0..3 -> N slice of 64
  const int r15  = lane & 15;
  const int kg   = lane >> 4;

  // A staging: c4 = f32x4 col, tr = row base; proven XOR-swizzled write.
  const int c4 = tid & 7;
  const int tr = tid >> 3;
  const float* aG = x + ((size_t)e * TPE + (size_t)mt * BM + tr) * DIN + c4 * 4;
  const int wrBase = tr * 64 + (((c4 >> 1) ^ ((tr >> 1) & 3)) << 4) + (c4 & 1) * 8;

  // frag read bases (chunk kg, swizzled by (r15>>1)&3)
  const int chz = (kg ^ ((r15 >> 1) & 3)) << 4;
  const int aRd = r15 * 64 + chz;                 // + mi*1024
  const int bRd = (wn * 64 + r15) * 64 + chz;     // + ni*1024 (wave-private region)

  // B DMA source: packed tile (e,nt,kt), chunks wn*4+i, per-lane 16B.
  const __bf16* bSrc =
      wp + ((size_t)(((e * 2 + nt) * 16) * 16 + wn * 4) * 64 + lane) * 8;
  // + kt*8192 per K-step, + i*512 per chunk.

  f32x4 sa0[4], sa1[4];

#define GLOADB(kt, dbuf)                                                     \
  { _Pragma("unroll") for (int i = 0; i < 4; ++i)                            \
      __builtin_amdgcn_global_load_lds(                                      \
          (const __attribute__((address_space(1))) void*)(bSrc +             \
              (size_t)(kt) * 8192 + i * 512),                                \
          (__attribute__((address_space(3))) void*)(&sB[dbuf][(wn * 4 + i) * 1024]), \
          16, 0, 0); }

#define ISSUEA(kt, Sr)                                                       \
  { _Pragma("unroll") for (int i = 0; i < 4; ++i)                            \
      Sr[i] = *(const f32x4*)(aG + (size_t)i * 32 * DIN + (kt) * BK); }

#define WRITEA(dbuf, Sr)                                                     \
  { _Pragma("unroll") for (int i = 0; i < 4; ++i) {                          \
      bf16x4 cc;                                                             \
      cc[0] = (__bf16)Sr[i][0]; cc[1] = (__bf16)Sr[i][1];                    \
      cc[2] = (__bf16)Sr[i][2]; cc[3] = (__bf16)Sr[i][3];                    \
      *(bf16x4*)(&sA[dbuf][wrBase + i * 2048]) = cc; } }

  f32x4 acc[8][4];
#pragma unroll
  for (int m = 0; m < 8; ++m)
#pragma unroll
    for (int n = 0; n < 4; ++n) acc[m][n] = (f32x4)0.f;

  // Prologue. VMEM issue order: B(0), A(0), A(1). WRITEA waits A(0) ->
  // compiler-counted vmcnt(4) (forces B(0)+A(0) done, A(1) stays in flight).
  GLOADB(0, 0);
  ISSUEA(0, sa0);
  ISSUEA(1, sa1);
  WRITEA(0, sa0);
  asm volatile("s_waitcnt lgkmcnt(0)" ::: "memory");
  __builtin_amdgcn_s_barrier();

  // Steady-state invariant at top of step t: outstanding = B(t)[4] + A(t+1)[4];
  // vmcnt(4) waits exactly B(t) (needed before ds_read of sB[d]).
#pragma unroll
  for (int t = 0; t < NKT; ++t) {
    const int d = t & 1;
    if (t == NKT - 1) {
      asm volatile("s_waitcnt vmcnt(0)" ::: "memory");   // only B(15) left
    } else {
      asm volatile("s_waitcnt vmcnt(4)" ::: "memory");
    }
    // P0: next-tile B DMA + frag reads for first MFMA half
    if (t + 1 < NKT) GLOADB(t + 1, d ^ 1);
    bf16x8 bfr[4], af[8];
#pragma unroll
    for (int ni = 0; ni < 4; ++ni)
      bfr[ni] = *(const bf16x8*)(&sB[d][bRd + ni * 1024]);
#pragma unroll
    for (int mi = 0; mi < 4; ++mi)
      af[mi] = *(const bf16x8*)(&sA[d][aRd + mi * 1024]);

    // P1: A-issue dist-2, then MFMA half 1
    if (t + 2 < NKT) {
      if (d == 0) { ISSUEA(t + 2, sa0); } else { ISSUEA(t + 2, sa1); }
    }
    __builtin_amdgcn_s_setprio(1);
#pragma unroll
    for (int mi = 0; mi < 4; ++mi)
#pragma unroll
      for (int ni = 0; ni < 4; ++ni)
        acc[mi][ni] = __builtin_amdgcn_mfma_f32_16x16x32_bf16(
            af[mi], bfr[ni], acc[mi][ni], 0, 0, 0);
    __builtin_amdgcn_s_setprio(0);

    // P2: remaining frag reads + A write (dist-1; reg-dep counted vmcnt)
#pragma unroll
    for (int mi = 4; mi < 8; ++mi)
      af[mi] = *(const bf16x8*)(&sA[d][aRd + mi * 1024]);
    if (t + 1 < NKT) {
      if (d == 0) { WRITEA(1, sa1); } else { WRITEA(0, sa0); }
    }

    // P3: MFMA half 2
    __builtin_amdgcn_s_setprio(1);
#pragma unroll
    for (int mi = 4; mi < 8; ++mi)
#pragma unroll
      for (int ni = 0; ni < 4; ++ni)
        acc[mi][ni] = __builtin_amdgcn_mfma_f32_16x16x32_bf16(
            af[mi], bfr[ni], acc[mi][ni], 0, 0, 0);
    __builtin_amdgcn_s_setprio(0);

    if (t + 1 < NKT) {
      asm volatile("s_waitcnt lgkmcnt(0)" ::: "memory");  // publish A writes
      __builtin_amdgcn_s_barrier();
    }
  }

  // Epilogue: C/D layout col = lane&15, row = (lane>>4)*4 + j  [m89/m91]
  float bv[4];
  const float* bp = bias + (size_t)e * DOUT + nt * BN + wn * 64 + r15;
#pragma unroll
  for (int n = 0; n < 4; ++n) bv[n] = bp[n * 16];

  const int q4 = (lane >> 4) * 4;
  float* Cb = out + ((size_t)e * TPE + (size_t)mt * BM) * DOUT + nt * BN + wn * 64;
#pragma unroll
  for (int m = 0; m < 8; ++m) {
#pragma unroll
    for (int j = 0; j < 4; ++j) {
      float* pr = Cb + (size_t)(m * 16 + q4 + j) * DOUT;
#pragma unroll
      for (int n = 0; n < 4; ++n)
        pr[n * 16 + r15] = acc[m][n][j] + bv[n];
    }
  }
#undef GLOADB
#undef ISSUEA
#undef WRITEA
}

// ---------------- fallback (ws too small): R2-proven kernel -----------------
__device__ __forceinline__ bf16x8 cvt8f(f32x4 lo, f32x4 hi) {
  bf16x8 r;
  r[0]=(__bf16)lo[0]; r[1]=(__bf16)lo[1]; r[2]=(__bf16)lo[2]; r[3]=(__bf16)lo[3];
  r[4]=(__bf16)hi[0]; r[5]=(__bf16)hi[1]; r[6]=(__bf16)hi[2]; r[7]=(__bf16)hi[3];
  return r;
}

__global__ __launch_bounds__(256)
void moe_fallback(const float* __restrict__ x, const float* __restrict__ w,
                  const float* __restrict__ bias, float* __restrict__ out) {
  __shared__ bf16x8 fA[2][512];
  __shared__ bf16x8 fB[2][512];
  int bid = blockIdx.x;
  int swz = (bid & 7) * 1024 + (bid >> 3);
  int e = swz >> 7, rr = swz & 127, mt = rr >> 2, nt = rr & 3;
  const int t = threadIdx.x, lane = t & 63, wave = t >> 6;
  const int wm = wave >> 1, wnn = wave & 1, r15 = lane & 15, kgf = lane >> 4;
  const int rs = r15 * 4 + (kgf ^ ((r15 >> 1) & 3));
  const int row0 = t >> 2, kg0 = t & 3;
  const int slot0 = row0 * 4 + (kg0 ^ ((row0 >> 1) & 3));
  const int slot1 = slot0 + 256;
  const float* Ab = x + ((size_t)e * TPE + (size_t)mt * 128) * DIN;
  const float* Bb = w + ((size_t)e * DOUT + (size_t)nt * 128) * DIN;
  const int offA0 = row0 * DIN + kg0 * 8, offA1 = offA0 + 64 * DIN;
  f32x4 a0l, a0h, a1l, a1h, b0l, b0h, b1l, b1h;
  auto LOAD = [&](int kt) {
    const float* pa0 = Ab + offA0 + kt * 32; const float* pa1 = Ab + offA1 + kt * 32;
    const float* pb0 = Bb + offA0 + kt * 32; const float* pb1 = Bb + offA1 + kt * 32;
    a0l = *(const f32x4*)(pa0); a0h = *(const f32x4*)(pa0 + 4);
    a1l = *(const f32x4*)(pa1); a1h = *(const f32x4*)(pa1 + 4);
    b0l = *(const f32x4*)(pb0); b0h = *(const f32x4*)(pb0 + 4);
    b1l = *(const f32x4*)(pb1); b1h = *(const f32x4*)(pb1 + 4);
  };
  auto STORE = [&](int buf) {
    fA[buf][slot0] = cvt8f(a0l, a0h); fA[buf][slot1] = cvt8f(a1l, a1h);
    fB[buf][slot0] = cvt8f(b0l, b0h); fB[buf][slot1] = cvt8f(b1l, b1h);
  };
  f32x4 acc[4][4];
#pragma unroll
  for (int m = 0; m < 4; ++m)
#pragma unroll
    for (int n = 0; n < 4; ++n) acc[m][n] = (f32x4)0.f;
  LOAD(0); STORE(0); __syncthreads();
  int cur = 0;
  for (int kt = 0; kt < NKT; ++kt) {
    if (kt + 1 < NKT) LOAD(kt + 1);
    bf16x8 af[4], bfr[4];
#pragma unroll
    for (int m = 0; m < 4; ++m) af[m] = fA[cur][wm * 256 + m * 64 + rs];
#pragma unroll
    for (int n = 0; n < 4; ++n) bfr[n] = fB[cur][wnn * 256 + n * 64 + rs];
#pragma unroll
    for (int m = 0; m < 4; ++m)
#pragma unroll
      for (int n = 0; n < 4; ++n)
        acc[m][n] = __builtin_amdgcn_mfma_f32_16x16x32_bf16(af[m], bfr[n], acc[m][n], 0, 0, 0);
    if (kt + 1 < NKT) { STORE(cur ^ 1); __syncthreads(); }
    cur ^= 1;
  }
  float bv[4];
  const float* bp = bias + (size_t)e * DOUT + nt * 128 + wnn * 64 + r15;
#pragma unroll
  for (int n = 0; n < 4; ++n) bv[n] = bp[n * 16];
  const int q4 = (lane >> 4) * 4;
  float* Cb = out + ((size_t)e * TPE + (size_t)mt * 128 + wm * 64) * DOUT + nt * 128 + wnn * 64;
#pragma unroll
  for (int m = 0; m < 4; ++m)
#pragma unroll
    for (int j = 0; j < 4; ++j) {
      float* pr = Cb + (size_t)(m * 16 + q4 + j) * DOUT;
#pragma unroll
      for (int n = 0; n < 4; ++n) pr[n * 16 + r15] = acc[m][n][j] + bv[n];
    }
}

extern "C" void kernel_launch(void* const* d_in, const int* in_sizes, int n_in,
                              void* d_out, int out_size, void* d_ws, size_t ws_size,
                              hipStream_t stream) {
  const float* x    = (const float*)d_in[0];
  // d_in[1] = num_experts_per_token (int64): balanced, unused
  const float* w    = (const float*)d_in[2];
  const float* bias = (const float*)d_in[3];
  float* out        = (float*)d_out;

  const size_t wElems = (size_t)NEXPERT * DOUT * DIN;     // 16.78M
  const size_t needWs = wElems * sizeof(__hip_bfloat16);  // 33.5MB
  dim3 block(256);

  if (ws_size >= needWs) {
    dim3 pgrid(wElems / 8 / 256);                         // 8192
    hipLaunchKernelGGL(pack_w_kernel, pgrid, block, 0, stream, w, (__bf16*)d_ws);
    dim3 grid(NEXPERT * (TPE / BM) * (DOUT / BN));        // 4096
    hipLaunchKernelGGL(moe_gemm8, grid, block, 0, stream,
                       x, (const __bf16*)d_ws, bias, out);
  } else {
    dim3 grid(NEXPERT * 32 * 4);                          // 8192
    hipLaunchKernelGGL(moe_fallback, grid, block, 0, stream, x, w, bias, out);
  }
}

// Round 10
// 355.133 us; speedup vs baseline: 3.3212x; 3.3212x over previous
//
#include <hip/hip_runtime.h>
#include <hip/hip_bf16.h>

// Grouped GEMM (MoE): out[t,o] = sum_k x[t,k]*W[e,o,k] + bias[e,o]
// E=64, 4096 tok/expert, D_IN=D_OUT=512, f32 in/out. bf16 MFMA.
// R10: 256x256 tile, BK=64, NKT=8, 8 waves (2M x 4N, wave tile 128x64).
// B: global_load_lds from W pre-packed bf16 (inverse-XOR-swizzled order, rows
// 128B / 8 chunks). A: reg-staged f32->bf16 dist-1 into XOR-swizzled LDS.
// B-frags held in regs per K-tile; A-frags read per phase (4 phases x 16 MFMA).
// ONE barrier + ONE lgkm drain per K-tile; all loads get ~1 tile of cover.
// 2 waves/SIMD (reg-capped: acc=128). XCD-aware block swizzle.

#define NEXPERT 64
#define DIN 512
#define DOUT 512
#define TPE 4096
#define BM 256
#define BN 256
#define BK 64
#define NKT 8

typedef __attribute__((ext_vector_type(8))) __bf16 bf16x8;
typedef __attribute__((ext_vector_type(4))) float f32x4;

// ---------------- W pack kernel: f32 W -> bf16 d_ws in gload_lds order ------
// Group G = ((((e*2+nt)*8 + kt)*32 + j)*64 + l) holds 8 bf16 of
//   W[e][o = nt*256 + j*8 + (l>>3)][k = kt*64 + ((l&7)^(l>>3))*8 .. +8]
// so a linear gload_lds fill (issue j covers 1KB) lands at LDS layout
//   byte(o,kc) = o*128 + ((kc ^ (o&7))<<4)   (8-chunk row XOR swizzle).
__global__ __launch_bounds__(256)
void pack_w_kernel(const float* __restrict__ w, __bf16* __restrict__ wp) {
  int S = blockIdx.x * 256 + threadIdx.x;   // 0 .. 2^21-1
  int l  = S & 63;
  int j  = (S >> 6) & 31;
  int kt = (S >> 11) & 7;
  int nt = (S >> 14) & 1;
  int e  = S >> 15;
  int o  = nt * 256 + j * 8 + (l >> 3);
  int kc = (l & 7) ^ (l >> 3);
  const float* src = w + ((size_t)(e * DOUT + o)) * DIN + kt * BK + kc * 8;
  f32x4 lo = *(const f32x4*)(src);
  f32x4 hi = *(const f32x4*)(src + 4);
  bf16x8 r;
  r[0]=(__bf16)lo[0]; r[1]=(__bf16)lo[1]; r[2]=(__bf16)lo[2]; r[3]=(__bf16)lo[3];
  r[4]=(__bf16)hi[0]; r[5]=(__bf16)hi[1]; r[6]=(__bf16)hi[2]; r[7]=(__bf16)hi[3];
  *(bf16x8*)(wp + (size_t)S * 8) = r;
}

// ---------------- main kernel ----------------------------------------------
__global__ __launch_bounds__(512, 2)
void moe_gemm256(const float* __restrict__ x, const __bf16* __restrict__ wp,
                 const float* __restrict__ bias, float* __restrict__ out) {
  __shared__ __align__(16) unsigned char sA[2][BM * BK * 2];  // 32KB each
  __shared__ __align__(16) unsigned char sB[2][BN * BK * 2];  // 32KB each

  // XCD swizzle: 2048 blocks = 8 XCDs x 256 contiguous.
  int bid  = blockIdx.x;
  int swzb = (bid & 7) * 256 + (bid >> 3);
  int e  = swzb >> 5;       // 32 blocks per expert
  int rr = swzb & 31;
  int mt = rr >> 1;         // 16 M-tiles; A-panel shared by 2 consecutive (nt inner)
  int nt = rr & 1;

  const int tid  = threadIdx.x;
  const int lane = tid & 63;
  const int wv   = tid >> 6;      // 0..7
  const int wm   = wv >> 2;       // 0..1: M slice of 128
  const int wn   = wv & 3;        // 0..3: N slice of 64
  const int r15  = lane & 15;
  const int kg   = lane >> 4;

  // frag-read XOR terms (chunk kc = kk*4+kg, row&7 == r15&7 everywhere)
  const int xt0 = ((kg)     ^ (r15 & 7)) << 4;
  const int xt1 = ((4 + kg) ^ (r15 & 7)) << 4;
  const int aRdBase = (wm * 128 + r15) * 128;   // + p*4096 + mi*2048 + xt
  const int bRdBase = (wn * 64  + r15) * 128;   // + ni*2048 + xt

  // A staging: thread owns row ar, k-half h (32 f32 per tile)
  const int ar = tid >> 1;        // 0..255
  const int h  = tid & 1;
  const float* aG = x + ((size_t)e * TPE + (size_t)mt * BM + ar) * DIN + h * 32;
  const int awr0 = ar * 128;      // + ((h*4+i2)^(ar&7))<<4

  // B DMA source (bf16 elems): per (kt, issue i): + kt*16384 + i*512
  const __bf16* bS0 = wp + (size_t)(e * 2 + nt) * 131072
                         + (size_t)(wv * 4) * 512 + (size_t)lane * 8;

  f32x4 sa[8];   // A stage (dist-1, single set)

#define GLOADB(kt, dbuf)                                                     \
  { _Pragma("unroll") for (int i = 0; i < 4; ++i)                            \
      __builtin_amdgcn_global_load_lds(                                      \
          (const __attribute__((address_space(1))) void*)(bS0 +              \
              (size_t)(kt) * 16384 + i * 512),                               \
          (__attribute__((address_space(3))) void*)(&sB[dbuf][(wv * 4 + i) * 1024]), \
          16, 0, 0); }

#define ISSUEA(kt)                                                           \
  { _Pragma("unroll") for (int i = 0; i < 8; ++i)                            \
      sa[i] = *(const f32x4*)(aG + (kt) * BK + i * 4); }

#define WRITEA(dbuf)                                                         \
  { _Pragma("unroll") for (int i2 = 0; i2 < 4; ++i2) {                       \
      bf16x8 cc;                                                             \
      cc[0]=(__bf16)sa[i2*2][0];   cc[1]=(__bf16)sa[i2*2][1];                \
      cc[2]=(__bf16)sa[i2*2][2];   cc[3]=(__bf16)sa[i2*2][3];                \
      cc[4]=(__bf16)sa[i2*2+1][0]; cc[5]=(__bf16)sa[i2*2+1][1];              \
      cc[6]=(__bf16)sa[i2*2+1][2]; cc[7]=(__bf16)sa[i2*2+1][3];              \
      *(bf16x8*)(&sA[dbuf][awr0 + (((h*4+i2) ^ (ar & 7)) << 4)]) = cc; } }

#define READB(d)                                                             \
  { _Pragma("unroll") for (int ni = 0; ni < 4; ++ni) {                       \
      bfr[ni][0] = *(const bf16x8*)(&sB[d][bRdBase + ni*2048 + xt0]);        \
      bfr[ni][1] = *(const bf16x8*)(&sB[d][bRdBase + ni*2048 + xt1]); } }

#define READA(p, d, af)                                                      \
  { _Pragma("unroll") for (int mi = 0; mi < 2; ++mi) {                       \
      af[mi][0] = *(const bf16x8*)(&sA[d][aRdBase + (p)*4096 + mi*2048 + xt0]); \
      af[mi][1] = *(const bf16x8*)(&sA[d][aRdBase + (p)*4096 + mi*2048 + xt1]); } }

#define MFMAP(p, af)                                                         \
  { __builtin_amdgcn_s_setprio(1);                                           \
    _Pragma("unroll") for (int mi = 0; mi < 2; ++mi)                         \
      _Pragma("unroll") for (int ni = 0; ni < 4; ++ni)                       \
        _Pragma("unroll") for (int kk = 0; kk < 2; ++kk)                     \
          acc[(p)*2+mi][ni] = __builtin_amdgcn_mfma_f32_16x16x32_bf16(       \
              af[mi][kk], bfr[ni][kk], acc[(p)*2+mi][ni], 0, 0, 0);          \
    __builtin_amdgcn_s_setprio(0); }

  f32x4 acc[8][4];
#pragma unroll
  for (int m = 0; m < 8; ++m)
#pragma unroll
    for (int n = 0; n < 4; ++n) acc[m][n] = (f32x4)0.f;

  // Prologue: B(0) DMA + A(0) stage (one-time full drain), publish, barrier.
  GLOADB(0, 0);
  ISSUEA(0);
  WRITEA(0);   // reg-dep drains A(0) (and B(0)) — prologue only
  asm volatile("s_waitcnt lgkmcnt(0)" ::: "memory");
  __builtin_amdgcn_s_barrier();

  bf16x8 bfr[4][2];

  // Tiles 0..6: stage t+1 at tile top (full-tile latency cover), one barrier.
#pragma unroll
  for (int t = 0; t < NKT - 1; ++t) {
    const int d = t & 1;
    GLOADB(t + 1, d ^ 1);
    ISSUEA(t + 1);
    READB(d);
    bf16x8 af0[2][2], af1[2][2], af2[2][2], af3[2][2];
    READA(0, d, af0);
    MFMAP(0, af0);
    READA(1, d, af1);
    MFMAP(1, af1);
    READA(2, d, af2);
    MFMAP(2, af2);
    READA(3, d, af3);
    WRITEA(d ^ 1);   // cvt reg-dep waits A(t+1) (drains B(t+1) too: both ~1 tile old)
    MFMAP(3, af3);   // store latency hides under last MFMA cluster
    asm volatile("s_waitcnt lgkmcnt(0)" ::: "memory");  // publish A writes
    __builtin_amdgcn_s_barrier();                       // B(t+1) DMA also landed
  }

  // Tail tile t=7 (d=1): no staging, no barrier.
  {
    const int d = 1;
    READB(d);
    bf16x8 af[2][2];
    READA(0, d, af); MFMAP(0, af);
    READA(1, d, af); MFMAP(1, af);
    READA(2, d, af); MFMAP(2, af);
    READA(3, d, af); MFMAP(3, af);
  }

  // Epilogue: C/D layout col = lane&15, row = (lane>>4)*4 + j  [m89/m91]
  float bv[4];
  const float* bp = bias + (size_t)e * DOUT + nt * BN + wn * 64 + r15;
#pragma unroll
  for (int n = 0; n < 4; ++n) bv[n] = bp[n * 16];

  const int q4 = (lane >> 4) * 4;
  float* Cb = out + ((size_t)e * TPE + (size_t)mt * BM + wm * 128) * DOUT
              + nt * BN + wn * 64;
#pragma unroll
  for (int m = 0; m < 8; ++m) {
#pragma unroll
    for (int j = 0; j < 4; ++j) {
      float* pr = Cb + (size_t)(m * 16 + q4 + j) * DOUT;
#pragma unroll
      for (int n = 0; n < 4; ++n)
        pr[n * 16 + r15] = acc[m][n][j] + bv[n];
    }
  }
#undef GLOADB
#undef ISSUEA
#undef WRITEA
#undef READB
#undef READA
#undef MFMAP
}

// ---------------- fallback (ws too small): R2-proven kernel -----------------
__device__ __forceinline__ bf16x8 cvt8f(f32x4 lo, f32x4 hi) {
  bf16x8 r;
  r[0]=(__bf16)lo[0]; r[1]=(__bf16)lo[1]; r[2]=(__bf16)lo[2]; r[3]=(__bf16)lo[3];
  r[4]=(__bf16)hi[0]; r[5]=(__bf16)hi[1]; r[6]=(__bf16)hi[2]; r[7]=(__bf16)hi[3];
  return r;
}

__global__ __launch_bounds__(256)
void moe_fallback(const float* __restrict__ x, const float* __restrict__ w,
                  const float* __restrict__ bias, float* __restrict__ out) {
  __shared__ bf16x8 fA[2][512];
  __shared__ bf16x8 fB[2][512];
  int bid = blockIdx.x;
  int swz = (bid & 7) * 1024 + (bid >> 3);
  int e = swz >> 7, rr = swz & 127, mt = rr >> 2, nt = rr & 3;
  const int t = threadIdx.x, lane = t & 63, wave = t >> 6;
  const int wm = wave >> 1, wnn = wave & 1, r15 = lane & 15, kgf = lane >> 4;
  const int rs = r15 * 4 + (kgf ^ ((r15 >> 1) & 3));
  const int row0 = t >> 2, kg0 = t & 3;
  const int slot0 = row0 * 4 + (kg0 ^ ((row0 >> 1) & 3));
  const int slot1 = slot0 + 256;
  const float* Ab = x + ((size_t)e * TPE + (size_t)mt * 128) * DIN;
  const float* Bb = w + ((size_t)e * DOUT + (size_t)nt * 128) * DIN;
  const int offA0 = row0 * DIN + kg0 * 8, offA1 = offA0 + 64 * DIN;
  f32x4 a0l, a0h, a1l, a1h, b0l, b0h, b1l, b1h;
  auto LOAD = [&](int kt) {
    const float* pa0 = Ab + offA0 + kt * 32; const float* pa1 = Ab + offA1 + kt * 32;
    const float* pb0 = Bb + offA0 + kt * 32; const float* pb1 = Bb + offA1 + kt * 32;
    a0l = *(const f32x4*)(pa0); a0h = *(const f32x4*)(pa0 + 4);
    a1l = *(const f32x4*)(pa1); a1h = *(const f32x4*)(pa1 + 4);
    b0l = *(const f32x4*)(pb0); b0h = *(const f32x4*)(pb0 + 4);
    b1l = *(const f32x4*)(pb1); b1h = *(const f32x4*)(pb1 + 4);
  };
  auto STORE = [&](int buf) {
    fA[buf][slot0] = cvt8f(a0l, a0h); fA[buf][slot1] = cvt8f(a1l, a1h);
    fB[buf][slot0] = cvt8f(b0l, b0h); fB[buf][slot1] = cvt8f(b1l, b1h);
  };
  f32x4 acc[4][4];
#pragma unroll
  for (int m = 0; m < 4; ++m)
#pragma unroll
    for (int n = 0; n < 4; ++n) acc[m][n] = (f32x4)0.f;
  LOAD(0); STORE(0); __syncthreads();
  int cur = 0;
  for (int kt = 0; kt < 16; ++kt) {
    if (kt + 1 < 16) LOAD(kt + 1);
    bf16x8 af[4], bfr[4];
#pragma unroll
    for (int m = 0; m < 4; ++m) af[m] = fA[cur][wm * 256 + m * 64 + rs];
#pragma unroll
    for (int n = 0; n < 4; ++n) bfr[n] = fB[cur][wnn * 256 + n * 64 + rs];
#pragma unroll
    for (int m = 0; m < 4; ++m)
#pragma unroll
      for (int n = 0; n < 4; ++n)
        acc[m][n] = __builtin_amdgcn_mfma_f32_16x16x32_bf16(af[m], bfr[n], acc[m][n], 0, 0, 0);
    if (kt + 1 < 16) { STORE(cur ^ 1); __syncthreads(); }
    cur ^= 1;
  }
  float bv[4];
  const float* bp = bias + (size_t)e * DOUT + nt * 128 + wnn * 64 + r15;
#pragma unroll
  for (int n = 0; n < 4; ++n) bv[n] = bp[n * 16];
  const int q4 = (lane >> 4) * 4;
  float* Cb = out + ((size_t)e * TPE + (size_t)mt * 128 + wm * 64) * DOUT + nt * 128 + wnn * 64;
#pragma unroll
  for (int m = 0; m < 4; ++m)
#pragma unroll
    for (int j = 0; j < 4; ++j) {
      float* pr = Cb + (size_t)(m * 16 + q4 + j) * DOUT;
#pragma unroll
      for (int n = 0; n < 4; ++n) pr[n * 16 + r15] = acc[m][n][j] + bv[n];
    }
}

extern "C" void kernel_launch(void* const* d_in, const int* in_sizes, int n_in,
                              void* d_out, int out_size, void* d_ws, size_t ws_size,
                              hipStream_t stream) {
  const float* x    = (const float*)d_in[0];
  // d_in[1] = num_experts_per_token (int64): balanced, unused
  const float* w    = (const float*)d_in[2];
  const float* bias = (const float*)d_in[3];
  float* out        = (float*)d_out;

  const size_t wElems = (size_t)NEXPERT * DOUT * DIN;     // 16.78M
  const size_t needWs = wElems * sizeof(__hip_bfloat16);  // 33.5MB

  if (ws_size >= needWs) {
    dim3 pgrid(wElems / 8 / 256);                         // 8192
    hipLaunchKernelGGL(pack_w_kernel, pgrid, dim3(256), 0, stream,
                       w, (__bf16*)d_ws);
    dim3 grid(NEXPERT * (TPE / BM) * (DOUT / BN));        // 64*16*2 = 2048
    hipLaunchKernelGGL(moe_gemm256, grid, dim3(512), 0, stream,
                       x, (const __bf16*)d_ws, bias, out);
  } else {
    dim3 grid(NEXPERT * 32 * 4);                          // 8192
    hipLaunchKernelGGL(moe_fallback, grid, dim3(256), 0, stream, x, w, bias, out);
  }
}

// Round 11
// 353.558 us; speedup vs baseline: 3.3360x; 1.0045x over previous
//
#include <hip/hip_runtime.h>
#include <hip/hip_bf16.h>

// Grouped GEMM (MoE): out[t,o] = sum_k x[t,k]*W[e,o,k] + bias[e,o]
// E=64, 4096 tok/expert, D_IN=D_OUT=512, f32 in/out. bf16 MFMA.
// R11 = R10 geometry (256x256, BK=64, NKT=8, 8 waves, wave tile 128x64,
// B via gload_lds from inverse-XOR-packed bf16 W, A reg-staged f32->bf16)
// + the 8-phase-template discipline (m196/m218): per-quadrant phases each
// {ds_read || stage-issue; s_barrier; lgkmcnt(0); setprio; 16 MFMA; setprio;
// s_barrier}, stage ops spread p0/p1, audited vmcnt(4) before WRITEA and a
// single end-of-tile vmcnt(0) publish with ~3 phases of latency cover.

#define NEXPERT 64
#define DIN 512
#define DOUT 512
#define TPE 4096
#define BM 256
#define BN 256
#define BK 64
#define NKT 8

typedef __attribute__((ext_vector_type(8))) __bf16 bf16x8;
typedef __attribute__((ext_vector_type(4))) float f32x4;

// ---------------- W pack kernel: f32 W -> bf16 d_ws in gload_lds order ------
// Group G = ((((e*2+nt)*8 + kt)*32 + j)*64 + l) holds 8 bf16 of
//   W[e][o = nt*256 + j*8 + (l>>3)][k = kt*64 + ((l&7)^(l>>3))*8 .. +8]
// so a linear gload_lds fill (issue j covers 1KB) lands at LDS layout
//   byte(o,kc) = o*128 + ((kc ^ (o&7))<<4)   (8-chunk row XOR swizzle).
__global__ __launch_bounds__(256)
void pack_w_kernel(const float* __restrict__ w, __bf16* __restrict__ wp) {
  int S = blockIdx.x * 256 + threadIdx.x;   // 0 .. 2^21-1
  int l  = S & 63;
  int j  = (S >> 6) & 31;
  int kt = (S >> 11) & 7;
  int nt = (S >> 14) & 1;
  int e  = S >> 15;
  int o  = nt * 256 + j * 8 + (l >> 3);
  int kc = (l & 7) ^ (l >> 3);
  const float* src = w + ((size_t)(e * DOUT + o)) * DIN + kt * BK + kc * 8;
  f32x4 lo = *(const f32x4*)(src);
  f32x4 hi = *(const f32x4*)(src + 4);
  bf16x8 r;
  r[0]=(__bf16)lo[0]; r[1]=(__bf16)lo[1]; r[2]=(__bf16)lo[2]; r[3]=(__bf16)lo[3];
  r[4]=(__bf16)hi[0]; r[5]=(__bf16)hi[1]; r[6]=(__bf16)hi[2]; r[7]=(__bf16)hi[3];
  *(bf16x8*)(wp + (size_t)S * 8) = r;
}

// ---------------- main kernel ----------------------------------------------
__global__ __launch_bounds__(512, 2)
void moe_gemm256(const float* __restrict__ x, const __bf16* __restrict__ wp,
                 const float* __restrict__ bias, float* __restrict__ out) {
  __shared__ __align__(16) unsigned char sA[2][BM * BK * 2];  // 32KB each
  __shared__ __align__(16) unsigned char sB[2][BN * BK * 2];  // 32KB each

  // XCD swizzle: 2048 blocks = 8 XCDs x 256 contiguous.
  int bid  = blockIdx.x;
  int swzb = (bid & 7) * 256 + (bid >> 3);
  int e  = swzb >> 5;       // 32 blocks per expert
  int rr = swzb & 31;
  int mt = rr >> 1;         // 16 M-tiles; A-panel shared by 2 consecutive (nt inner)
  int nt = rr & 1;

  const int tid  = threadIdx.x;
  const int lane = tid & 63;
  const int wv   = tid >> 6;      // 0..7
  const int wm   = wv >> 2;       // 0..1: M slice of 128
  const int wn   = wv & 3;        // 0..3: N slice of 64
  const int r15  = lane & 15;
  const int kg   = lane >> 4;

  // frag-read XOR terms (chunk kc = kk*4+kg, row&7 == r15&7 everywhere)
  const int xt0 = ((kg)     ^ (r15 & 7)) << 4;
  const int xt1 = ((4 + kg) ^ (r15 & 7)) << 4;
  const int aRdBase = (wm * 128 + r15) * 128;   // + p*4096 + mi*2048 + xt
  const int bRdBase = (wn * 64  + r15) * 128;   // + ni*2048 + xt

  // A staging: thread owns row ar, k-half h (32 f32 per tile)
  const int ar = tid >> 1;        // 0..255
  const int h  = tid & 1;
  const float* aG = x + ((size_t)e * TPE + (size_t)mt * BM + ar) * DIN + h * 32;
  const int awr0 = ar * 128;      // + ((h*4+i2)^(ar&7))<<4

  // B DMA source (bf16 elems): per (kt, issue i): + kt*16384 + i*512
  const __bf16* bS0 = wp + (size_t)(e * 2 + nt) * 131072
                         + (size_t)(wv * 4) * 512 + (size_t)lane * 8;

  f32x4 sa[8];   // A stage (dist-1, single set)

#define GLOADB(kt, dbuf)                                                     \
  { _Pragma("unroll") for (int i = 0; i < 4; ++i)                            \
      __builtin_amdgcn_global_load_lds(                                      \
          (const __attribute__((address_space(1))) void*)(bS0 +              \
              (size_t)(kt) * 16384 + i * 512),                               \
          (__attribute__((address_space(3))) void*)(&sB[dbuf][(wv * 4 + i) * 1024]), \
          16, 0, 0); }

#define ISSUEA(kt)                                                           \
  { _Pragma("unroll") for (int i = 0; i < 8; ++i)                            \
      sa[i] = *(const f32x4*)(aG + (kt) * BK + i * 4); }

#define WRITEA(dbuf)                                                         \
  { _Pragma("unroll") for (int i2 = 0; i2 < 4; ++i2) {                       \
      bf16x8 cc;                                                             \
      cc[0]=(__bf16)sa[i2*2][0];   cc[1]=(__bf16)sa[i2*2][1];                \
      cc[2]=(__bf16)sa[i2*2][2];   cc[3]=(__bf16)sa[i2*2][3];                \
      cc[4]=(__bf16)sa[i2*2+1][0]; cc[5]=(__bf16)sa[i2*2+1][1];              \
      cc[6]=(__bf16)sa[i2*2+1][2]; cc[7]=(__bf16)sa[i2*2+1][3];              \
      *(bf16x8*)(&sA[dbuf][awr0 + (((h*4+i2) ^ (ar & 7)) << 4)]) = cc; } }

#define READB(d)                                                             \
  { _Pragma("unroll") for (int ni = 0; ni < 4; ++ni) {                       \
      bfr[ni][0] = *(const bf16x8*)(&sB[d][bRdBase + ni*2048 + xt0]);        \
      bfr[ni][1] = *(const bf16x8*)(&sB[d][bRdBase + ni*2048 + xt1]); } }

#define READA(p, d, af)                                                      \
  { _Pragma("unroll") for (int mi = 0; mi < 2; ++mi) {                       \
      af[mi][0] = *(const bf16x8*)(&sA[d][aRdBase + (p)*4096 + mi*2048 + xt0]); \
      af[mi][1] = *(const bf16x8*)(&sA[d][aRdBase + (p)*4096 + mi*2048 + xt1]); } }

// phase discipline: bar; lgkm(0); sched_barrier; prio1; 16 MFMA; prio0; bar
#define PHASE_SYNC_IN()                                                      \
  { __builtin_amdgcn_s_barrier();                                            \
    asm volatile("s_waitcnt lgkmcnt(0)" ::: "memory");                       \
    __builtin_amdgcn_sched_barrier(0); }

#define MFMAP(p, af)                                                         \
  { __builtin_amdgcn_s_setprio(1);                                           \
    _Pragma("unroll") for (int mi = 0; mi < 2; ++mi)                         \
      _Pragma("unroll") for (int ni = 0; ni < 4; ++ni)                       \
        _Pragma("unroll") for (int kk = 0; kk < 2; ++kk)                     \
          acc[(p)*2+mi][ni] = __builtin_amdgcn_mfma_f32_16x16x32_bf16(       \
              af[mi][kk], bfr[ni][kk], acc[(p)*2+mi][ni], 0, 0, 0);          \
    __builtin_amdgcn_s_setprio(0); }

  f32x4 acc[8][4];
#pragma unroll
  for (int m = 0; m < 8; ++m)
#pragma unroll
    for (int n = 0; n < 4; ++n) acc[m][n] = (f32x4)0.f;

  // Prologue: B(0) DMA then A(0) (A younger: WRITEA's reg-dep drains both).
  GLOADB(0, 0);
  ISSUEA(0);
  WRITEA(0);
  asm volatile("s_waitcnt lgkmcnt(0)" ::: "memory");
  __builtin_amdgcn_s_barrier();

#pragma unroll
  for (int t = 0; t < NKT; ++t) {
    const int d = t & 1;
    const bool stage = (t + 1 < NKT);
    bf16x8 bfr[4][2];

    // ---- phase 0: A(t+1) reg-issue (oldest) | B-frags + A-q0 ds_reads ----
    if (stage) ISSUEA(t + 1);                    // vmem queue: A x8
    READB(d);                                    // 8 ds_read_b128
    bf16x8 af0[2][2];
    READA(0, d, af0);                            // 4 ds_read_b128
    PHASE_SYNC_IN();
    MFMAP(0, af0);
    __builtin_amdgcn_s_barrier();

    // ---- phase 1: B(t+1) DMA issue (youngest) | A-q1 ds_reads ----
    if (stage) GLOADB(t + 1, d ^ 1);             // vmem queue: A x8 + B x4
    bf16x8 af1[2][2];
    READA(1, d, af1);
    PHASE_SYNC_IN();
    MFMAP(1, af1);
    __builtin_amdgcn_s_barrier();

    // ---- phase 2: pure compute ----
    bf16x8 af2[2][2];
    READA(2, d, af2);
    PHASE_SYNC_IN();
    MFMAP(2, af2);
    __builtin_amdgcn_s_barrier();

    // ---- phase 3: A convert+write (vmcnt(4): A done, B stays in flight) ----
    bf16x8 af3[2][2];
    READA(3, d, af3);
    if (stage) {
      asm volatile("s_waitcnt vmcnt(4)" ::: "memory");  // A(t+1) x8 (oldest) done
      WRITEA(d ^ 1);
    }
    PHASE_SYNC_IN();                             // drains own ds_writes too
    MFMAP(3, af3);
    if (stage) {
      // publish point: B(t+1) issued 3 phases ago (~600-900cyc cover)
      asm volatile("s_waitcnt vmcnt(0)" ::: "memory");
    }
    __builtin_amdgcn_s_barrier();                // sA/sB[d^1] now valid for all
  }

  // Epilogue: C/D layout col = lane&15, row = (lane>>4)*4 + j  [m89/m91]
  float bv[4];
  const float* bp = bias + (size_t)e * DOUT + nt * BN + wn * 64 + r15;
#pragma unroll
  for (int n = 0; n < 4; ++n) bv[n] = bp[n * 16];

  const int q4 = (lane >> 4) * 4;
  float* Cb = out + ((size_t)e * TPE + (size_t)mt * BM + wm * 128) * DOUT
              + nt * BN + wn * 64;
#pragma unroll
  for (int m = 0; m < 8; ++m) {
#pragma unroll
    for (int j = 0; j < 4; ++j) {
      float* pr = Cb + (size_t)(m * 16 + q4 + j) * DOUT;
#pragma unroll
      for (int n = 0; n < 4; ++n)
        pr[n * 16 + r15] = acc[m][n][j] + bv[n];
    }
  }
#undef GLOADB
#undef ISSUEA
#undef WRITEA
#undef READB
#undef READA
#undef PHASE_SYNC_IN
#undef MFMAP
}

// ---------------- fallback (ws too small): R2-proven kernel -----------------
__device__ __forceinline__ bf16x8 cvt8f(f32x4 lo, f32x4 hi) {
  bf16x8 r;
  r[0]=(__bf16)lo[0]; r[1]=(__bf16)lo[1]; r[2]=(__bf16)lo[2]; r[3]=(__bf16)lo[3];
  r[4]=(__bf16)hi[0]; r[5]=(__bf16)hi[1]; r[6]=(__bf16)hi[2]; r[7]=(__bf16)hi[3];
  return r;
}

__global__ __launch_bounds__(256)
void moe_fallback(const float* __restrict__ x, const float* __restrict__ w,
                  const float* __restrict__ bias, float* __restrict__ out) {
  __shared__ bf16x8 fA[2][512];
  __shared__ bf16x8 fB[2][512];
  int bid = blockIdx.x;
  int swz = (bid & 7) * 1024 + (bid >> 3);
  int e = swz >> 7, rr = swz & 127, mt = rr >> 2, nt = rr & 3;
  const int t = threadIdx.x, lane = t & 63, wave = t >> 6;
  const int wm = wave >> 1, wnn = wave & 1, r15 = lane & 15, kgf = lane >> 4;
  const int rs = r15 * 4 + (kgf ^ ((r15 >> 1) & 3));
  const int row0 = t >> 2, kg0 = t & 3;
  const int slot0 = row0 * 4 + (kg0 ^ ((row0 >> 1) & 3));
  const int slot1 = slot0 + 256;
  const float* Ab = x + ((size_t)e * TPE + (size_t)mt * 128) * DIN;
  const float* Bb = w + ((size_t)e * DOUT + (size_t)nt * 128) * DIN;
  const int offA0 = row0 * DIN + kg0 * 8, offA1 = offA0 + 64 * DIN;
  f32x4 a0l, a0h, a1l, a1h, b0l, b0h, b1l, b1h;
  auto LOAD = [&](int kt) {
    const float* pa0 = Ab + offA0 + kt * 32; const float* pa1 = Ab + offA1 + kt * 32;
    const float* pb0 = Bb + offA0 + kt * 32; const float* pb1 = Bb + offA1 + kt * 32;
    a0l = *(const f32x4*)(pa0); a0h = *(const f32x4*)(pa0 + 4);
    a1l = *(const f32x4*)(pa1); a1h = *(const f32x4*)(pa1 + 4);
    b0l = *(const f32x4*)(pb0); b0h = *(const f32x4*)(pb0 + 4);
    b1l = *(const f32x4*)(pb1); b1h = *(const f32x4*)(pb1 + 4);
  };
  auto STORE = [&](int buf) {
    fA[buf][slot0] = cvt8f(a0l, a0h); fA[buf][slot1] = cvt8f(a1l, a1h);
    fB[buf][slot0] = cvt8f(b0l, b0h); fB[buf][slot1] = cvt8f(b1l, b1h);
  };
  f32x4 acc[4][4];
#pragma unroll
  for (int m = 0; m < 4; ++m)
#pragma unroll
    for (int n = 0; n < 4; ++n) acc[m][n] = (f32x4)0.f;
  LOAD(0); STORE(0); __syncthreads();
  int cur = 0;
  for (int kt = 0; kt < 16; ++kt) {
    if (kt + 1 < 16) LOAD(kt + 1);
    bf16x8 af[4], bfr[4];
#pragma unroll
    for (int m = 0; m < 4; ++m) af[m] = fA[cur][wm * 256 + m * 64 + rs];
#pragma unroll
    for (int n = 0; n < 4; ++n) bfr[n] = fB[cur][wnn * 256 + n * 64 + rs];
#pragma unroll
    for (int m = 0; m < 4; ++m)
#pragma unroll
      for (int n = 0; n < 4; ++n)
        acc[m][n] = __builtin_amdgcn_mfma_f32_16x16x32_bf16(af[m], bfr[n], acc[m][n], 0, 0, 0);
    if (kt + 1 < 16) { STORE(cur ^ 1); __syncthreads(); }
    cur ^= 1;
  }
  float bv[4];
  const float* bp = bias + (size_t)e * DOUT + nt * 128 + wnn * 64 + r15;
#pragma unroll
  for (int n = 0; n < 4; ++n) bv[n] = bp[n * 16];
  const int q4 = (lane >> 4) * 4;
  float* Cb = out + ((size_t)e * TPE + (size_t)mt * 128 + wm * 64) * DOUT + nt * 128 + wnn * 64;
#pragma unroll
  for (int m = 0; m < 4; ++m)
#pragma unroll
    for (int j = 0; j < 4; ++j) {
      float* pr = Cb + (size_t)(m * 16 + q4 + j) * DOUT;
#pragma unroll
      for (int n = 0; n < 4; ++n) pr[n * 16 + r15] = acc[m][n][j] + bv[n];
    }
}

extern "C" void kernel_launch(void* const* d_in, const int* in_sizes, int n_in,
                              void* d_out, int out_size, void* d_ws, size_t ws_size,
                              hipStream_t stream) {
  const float* x    = (const float*)d_in[0];
  // d_in[1] = num_experts_per_token (int64): balanced, unused
  const float* w    = (const float*)d_in[2];
  const float* bias = (const float*)d_in[3];
  float* out        = (float*)d_out;

  const size_t wElems = (size_t)NEXPERT * DOUT * DIN;     // 16.78M
  const size_t needWs = wElems * sizeof(__hip_bfloat16);  // 33.5MB

  if (ws_size >= needWs) {
    dim3 pgrid(wElems / 8 / 256);                         // 8192
    hipLaunchKernelGGL(pack_w_kernel, pgrid, dim3(256), 0, stream,
                       w, (__bf16*)d_ws);
    dim3 grid(NEXPERT * (TPE / BM) * (DOUT / BN));        // 64*16*2 = 2048
    hipLaunchKernelGGL(moe_gemm256, grid, dim3(512), 0, stream,
                       x, (const __bf16*)d_ws, bias, out);
  } else {
    dim3 grid(NEXPERT * 32 * 4);                          // 8192
    hipLaunchKernelGGL(moe_fallback, grid, dim3(256), 0, stream, x, w, bias, out);
  }
}